// Round 3
// baseline (716.381 us; speedup 1.0000x reference)
//
#include <hip/hip_runtime.h>
#include <hip/hip_cooperative_groups.h>

namespace cg = cooperative_groups;

// CrossAttention on MI355X (gfx950), bf16 MFMA pipeline.
// ws usage: ONLY 2MB (w_o bf16 frags). Q/K/V frag buffers are hosted inside
// d_out (consumed before the final outputs are written; grid.sync() separates
// the read phase from the write phase in the cooperative attention kernel).

typedef float f32x4 __attribute__((ext_vector_type(4)));
typedef short bf16x8 __attribute__((ext_vector_type(8)));
typedef short s16x4 __attribute__((ext_vector_type(4)));

#define QSCALE 0.18033688011112042f   // 0.125 * log2(e); folded into Q so P = exp2(S)

// f32 -> bf16 round-to-nearest-even
__device__ __forceinline__ short f2bf(float x) {
    union { float f; unsigned int u; } v;
    v.f = x;
    unsigned int r = v.u + 0x7FFFu + ((v.u >> 16) & 1u);
    return (short)(r >> 16);
}

// D[16x16] = A[16x32] * B[32x16] + C.  A lane: row=l&15, k=(l>>4)*8+j.
// B lane: col=l&15, k=(l>>4)*8+j.  D lane: col=l&15, row=(l>>4)*4+reg.
__device__ __forceinline__ f32x4 mfma_bf16(bf16x8 a, bf16x8 b, f32x4 c) {
    return __builtin_amdgcn_mfma_f32_16x16x32_bf16(a, b, c, 0, 0, 0);
}

// ---------------------------------------------------------------------------
// w_o [1024][1024] f32 -> bf16 B-frag-major: idx = (col>>4)*16384 + (k>>3)*128
// + (col&15)*8 + (k&7).  (2MB, the only d_ws use.)
// ---------------------------------------------------------------------------
__global__ void wo_conv_kernel(const float* __restrict__ wo, short* __restrict__ wof) {
    const int t = blockIdx.x * 256 + threadIdx.x;   // 0..131071
    const int col = t >> 7, k8 = t & 127;
    const float* p = wo + (size_t)col * 1024 + k8 * 8;
    float4 a0 = *(const float4*)p;
    float4 a1 = *(const float4*)(p + 4);
    bf16x8 v;
    v[0]=f2bf(a0.x); v[1]=f2bf(a0.y); v[2]=f2bf(a0.z); v[3]=f2bf(a0.w);
    v[4]=f2bf(a1.x); v[5]=f2bf(a1.y); v[6]=f2bf(a1.z); v[7]=f2bf(a1.w);
    *(bf16x8*)(wof + ((col >> 4) * 16384 + k8 * 128 + (col & 15) * 8)) = v;
}

// ---------------------------------------------------------------------------
// Projection GEMM: C[row,col] = sum_k A[row,k]*W[col,k] + bias[col]
// MODE 0: Q (KDIM=1024, *QSCALE, out -> Q A-frag layout)
// MODE 1: K (KDIM=768, out -> K B-frag layout)
// MODE 2: V (KDIM=768, out -> V B-frag layout, m-as-K ordering)
// Tiles: 128x128, BK=64, 4 waves (each 64x64), LDS bf16 tiles with XOR swizzle.
// ---------------------------------------------------------------------------
template <int MODE>
__global__ __launch_bounds__(256, 2) void proj_kernel(
    const float* __restrict__ Ain, const float* __restrict__ W,
    const float* __restrict__ bias, short* __restrict__ outb)
{
    constexpr int KDIM = (MODE == 1 || MODE == 2) ? 768 : 1024;
    __shared__ short Alds[128 * 64];
    __shared__ short Wlds[128 * 64];

    const int tid  = threadIdx.x;
    const int lane = tid & 63;
    const int g = lane >> 4, c = lane & 15;
    const int wid = tid >> 6;
    const int wm = wid >> 1, wn = wid & 1;
    const int bn = blockIdx.x, bm = blockIdx.y;

    const int srow = tid >> 3;        // 0..31 staging row within pass
    const int scol = (tid & 7) * 8;   // 0..56 staging col (8 elems)

    f32x4 acc[4][4] = {};

    for (int kt = 0; kt < KDIM / 64; ++kt) {
        const int k0 = kt * 64;
        __syncthreads();
        #pragma unroll
        for (int p = 0; p < 4; ++p) {
            const int r = p * 32 + srow;
            bf16x8 av, wv;
            {
                const float* ap = Ain + (size_t)(bm * 128 + r) * KDIM + k0 + scol;
                float4 a0 = *(const float4*)ap;
                float4 a1 = *(const float4*)(ap + 4);
                av[0]=f2bf(a0.x); av[1]=f2bf(a0.y); av[2]=f2bf(a0.z); av[3]=f2bf(a0.w);
                av[4]=f2bf(a1.x); av[5]=f2bf(a1.y); av[6]=f2bf(a1.z); av[7]=f2bf(a1.w);
            }
            {
                const float* wp = W + (size_t)(bn * 128 + r) * KDIM + k0 + scol;
                float4 w0 = *(const float4*)wp;
                float4 w1 = *(const float4*)(wp + 4);
                wv[0]=f2bf(w0.x); wv[1]=f2bf(w0.y); wv[2]=f2bf(w0.z); wv[3]=f2bf(w0.w);
                wv[4]=f2bf(w1.x); wv[5]=f2bf(w1.y); wv[6]=f2bf(w1.z); wv[7]=f2bf(w1.w);
            }
            const int byt = (r * 128 + scol * 2) ^ ((r & 7) << 4);  // XOR swizzle
            *(bf16x8*)((char*)Alds + byt) = av;
            *(bf16x8*)((char*)Wlds + byt) = wv;
        }
        __syncthreads();
        #pragma unroll
        for (int kc = 0; kc < 2; ++kc) {
            bf16x8 af[4], bfr[4];
            #pragma unroll
            for (int t = 0; t < 4; ++t) {
                const int ra = wm * 64 + t * 16 + c;
                af[t]  = *(const bf16x8*)((const char*)Alds +
                          ((ra * 128 + (kc * 32 + g * 8) * 2) ^ ((ra & 7) << 4)));
                const int rb = wn * 64 + t * 16 + c;
                bfr[t] = *(const bf16x8*)((const char*)Wlds +
                          ((rb * 128 + (kc * 32 + g * 8) * 2) ^ ((rb & 7) << 4)));
            }
            #pragma unroll
            for (int i = 0; i < 4; ++i)
                #pragma unroll
                for (int j = 0; j < 4; ++j)
                    acc[i][j] = mfma_bf16(af[i], bfr[j], acc[i][j]);
        }
    }

    // epilogue -> frag-major layouts (bijective per (b,h): verified bit fields)
    #pragma unroll
    for (int j = 0; j < 4; ++j) {
        const int col = bn * 128 + wn * 64 + j * 16 + c;
        const float bv = bias[col];
        #pragma unroll
        for (int i = 0; i < 4; ++i) {
            #pragma unroll
            for (int r = 0; r < 4; ++r) {
                const int row = bm * 128 + wm * 64 + i * 16 + g * 4 + r;
                float v = acc[i][j][r] + bv;
                if constexpr (MODE == 0) v *= QSCALE;
                const int b = row >> 10, s = row & 1023;
                const int h = col >> 6,  d = col & 63;
                const size_t base = (size_t)(b * 16 + h) * 65536;
                size_t idx;
                if constexpr (MODE == 0)       // A-frag: [ntile][kc][g][c][j]
                    idx = base + (size_t)((s >> 4) * 1024 + (d >> 5) * 512 +
                          ((d >> 3) & 3) * 128 + (s & 15) * 8 + (d & 7));
                else if constexpr (MODE == 1)  // B-frag: [mtile][dchunk][c][j]
                    idx = base + (size_t)((s >> 4) * 1024 + (d >> 3) * 128 +
                          (s & 15) * 8 + (d & 7));
                else                           // V B-frag: [m32][dtile][g][c][j] (k = m)
                    idx = base + (size_t)((s >> 5) * 2048 + (d >> 4) * 512 +
                          ((s >> 3) & 3) * 128 + (d & 15) * 8 + (s & 7));
                outb[idx] = f2bf(v);
            }
        }
    }
}

// ---------------------------------------------------------------------------
// Cooperative attention + fused O-projection.
// Block = (batch b, 32-row query tile), 512 threads (8 waves), grid 256 = #CUs.
// Phase 1 (heads loop): read qf/kf/vf (hosted in d_out), stage Oh in LDS.
// grid.sync(); Phase 2: write attn-mean (clobbers qf/kf hosting) + tail GEMM
// out = Oh @ w_o^T + b_o (clobbers vf hosting).
// ---------------------------------------------------------------------------
__global__ __launch_bounds__(512, 2) void attn_kernel(
    const short* Qf, const short* Kf, const short* Vf,
    const short* Wof, const float* bo, float* outp)
{
    __shared__ short Ohlds[32 * 1024];  // 64KB: per-block attn output, swizzled
    __shared__ float pbuf[8][32 * 36];  // per-wave P bounce
    __shared__ float red[8][32];        // per-wave partial row sums
    __shared__ float rinv[32];          // 1 / row sum
    __shared__ float oacc[32][68];      // O accumulator across waves

    const int tid  = threadIdx.x;
    const int lane = tid & 63;
    const int w = tid >> 6;
    const int g = lane >> 4, c = lane & 15;
    const int b = blockIdx.x >> 5, nt = blockIdx.x & 31;

    const int zn = tid >> 4, zd = (tid & 15) * 4;   // this thread's O slot
    *(f32x4*)&oacc[zn][zd] = (f32x4){0.f, 0.f, 0.f, 0.f};

    f32x4 am[2][8] = {};  // sum over heads of normalized P (for attn.mean)

    for (int h = 0; h < 16; ++h) {
        const size_t hb = (size_t)(b * 16 + h) * 65536;

        bf16x8 qfr[2][2];
        #pragma unroll
        for (int at = 0; at < 2; ++at)
            #pragma unroll
            for (int kc = 0; kc < 2; ++kc)
                qfr[at][kc] = *(const bf16x8*)(Qf + hb +
                    (size_t)((nt * 2 + at) * 1024 + kc * 512 + g * 128 + c * 8));

        // S = Q K^T (scaled), wave's 128-col slice
        f32x4 p[2][8] = {};
        #pragma unroll
        for (int mt = 0; mt < 8; ++mt) {
            const int mtile = w * 8 + mt;
            #pragma unroll
            for (int kc = 0; kc < 2; ++kc) {
                bf16x8 kfr = *(const bf16x8*)(Kf + hb +
                    (size_t)(mtile * 1024 + (kc * 4 + g) * 128 + c * 8));
                #pragma unroll
                for (int at = 0; at < 2; ++at)
                    p[at][mt] = mfma_bf16(qfr[at][kc], kfr, p[at][mt]);
            }
        }

        // clamp + exp2 + per-lane partial row sums
        f32x4 rs[2] = {};
        #pragma unroll
        for (int at = 0; at < 2; ++at)
            #pragma unroll
            for (int mt = 0; mt < 8; ++mt) {
                f32x4 v = p[at][mt];
                #pragma unroll
                for (int r = 0; r < 4; ++r)
                    v[r] = exp2f(fminf(fmaxf(v[r], -60.f), 60.f));
                p[at][mt] = v;
                rs[at] += v;
            }
        #pragma unroll
        for (int off = 1; off < 16; off <<= 1)
            #pragma unroll
            for (int at = 0; at < 2; ++at)
                #pragma unroll
                for (int r = 0; r < 4; ++r)
                    rs[at][r] += __shfl_xor(rs[at][r], off);
        if (c == 0) {
            #pragma unroll
            for (int at = 0; at < 2; ++at)
                #pragma unroll
                for (int r = 0; r < 4; ++r)
                    red[w][at * 16 + g * 4 + r] = rs[at][r];
        }
        __syncthreads();                               // (1)
        if (tid < 32) {
            float s = 0.f;
            #pragma unroll
            for (int ww = 0; ww < 8; ++ww) s += red[ww][tid];
            rinv[tid] = 1.0f / s;
        }
        __syncthreads();                               // (2)

        f32x4 rv[2];
        rv[0] = *(const f32x4*)&rinv[g * 4];
        rv[1] = *(const f32x4*)&rinv[16 + g * 4];
        #pragma unroll
        for (int at = 0; at < 2; ++at)
            #pragma unroll
            for (int mt = 0; mt < 8; ++mt) {
                p[at][mt] *= rv[at];
                am[at][mt] += p[at][mt];
            }

        // PV: bounce 32x32 P chunks through per-wave LDS to build A-frags
        float* pb = pbuf[w];
        f32x4 oa[2][4] = {};
        #pragma unroll
        for (int ks = 0; ks < 4; ++ks) {
            #pragma unroll
            for (int at = 0; at < 2; ++at)
                #pragma unroll
                for (int m2 = 0; m2 < 2; ++m2)
                    #pragma unroll
                    for (int r = 0; r < 4; ++r)
                        pb[(at * 16 + g * 4 + r) * 36 + m2 * 16 + c] = p[at][ks * 2 + m2][r];
            asm volatile("s_waitcnt lgkmcnt(0)" ::: "memory");
            bf16x8 pa[2];
            #pragma unroll
            for (int at = 0; at < 2; ++at) {
                f32x4 lo = *(const f32x4*)&pb[(at * 16 + c) * 36 + g * 8];
                f32x4 hi = *(const f32x4*)&pb[(at * 16 + c) * 36 + g * 8 + 4];
                bf16x8 t;
                t[0]=f2bf(lo[0]); t[1]=f2bf(lo[1]); t[2]=f2bf(lo[2]); t[3]=f2bf(lo[3]);
                t[4]=f2bf(hi[0]); t[5]=f2bf(hi[1]); t[6]=f2bf(hi[2]); t[7]=f2bf(hi[3]);
                pa[at] = t;
            }
            asm volatile("s_waitcnt lgkmcnt(0)" ::: "memory");
            #pragma unroll
            for (int dt = 0; dt < 4; ++dt) {
                bf16x8 vfr = *(const bf16x8*)(Vf + hb +
                    (size_t)(((w * 4 + ks) * 4 + dt) * 512 + g * 128 + c * 8));
                #pragma unroll
                for (int at = 0; at < 2; ++at)
                    oa[at][dt] = mfma_bf16(pa[at], vfr, oa[at][dt]);
            }
        }
        #pragma unroll
        for (int at = 0; at < 2; ++at)
            #pragma unroll
            for (int dt = 0; dt < 4; ++dt)
                #pragma unroll
                for (int r = 0; r < 4; ++r)
                    atomicAdd(&oacc[at * 16 + g * 4 + r][dt * 16 + c], oa[at][dt][r]);
        __syncthreads();                               // (3)
        {
            f32x4 ov = *(const f32x4*)&oacc[zn][zd];
            *(f32x4*)&oacc[zn][zd] = (f32x4){0.f, 0.f, 0.f, 0.f};
            s16x4 pk;
            pk[0] = f2bf(ov[0]); pk[1] = f2bf(ov[1]);
            pk[2] = f2bf(ov[2]); pk[3] = f2bf(ov[3]);
            unsigned byt = (unsigned)(zn * 2048 + (h * 64 + zd) * 2);
            byt ^= (unsigned)((zn & 7) << 4);          // XOR swizzle
            *(s16x4*)((char*)Ohlds + byt) = pk;
        }
    }

    // ---- all blocks done reading qf/kf/vf hosted in d_out ----
    cg::this_grid().sync();

    // attn.mean(heads) -> out1 (clobbers qf/kf hosting; frees am registers)
    float* aout = outp + 8388608 + (size_t)b * 1048576;
    #pragma unroll
    for (int at = 0; at < 2; ++at)
        #pragma unroll
        for (int mt = 0; mt < 8; ++mt)
            #pragma unroll
            for (int r = 0; r < 4; ++r) {
                const int n = nt * 32 + at * 16 + g * 4 + r;
                const int m = w * 128 + mt * 16 + c;
                aout[(size_t)n * 1024 + m] = am[at][mt][r] * 0.0625f;
            }

    // tail GEMM: out[32 rows][1024] = Ohlds(32x1024) @ w_o^T + b_o.
    // wave w owns cols [w*128, w*128+128). (clobbers vf hosting in out0)
    f32x4 acc2[2][8] = {};
    for (int kt = 0; kt < 32; ++kt) {
        bf16x8 afr[2];
        #pragma unroll
        for (int at = 0; at < 2; ++at) {
            const int row = at * 16 + c;
            unsigned byt = (unsigned)(row * 2048 + (kt * 32 + g * 8) * 2);
            byt ^= (unsigned)((row & 7) << 4);
            afr[at] = *(const bf16x8*)((const char*)Ohlds + byt);
        }
        #pragma unroll
        for (int ct = 0; ct < 8; ++ct) {
            bf16x8 bfr = *(const bf16x8*)(Wof +
                ((w * 8 + ct) * 16384 + (kt * 4 + g) * 128 + c * 8));
            #pragma unroll
            for (int at = 0; at < 2; ++at)
                acc2[at][ct] = mfma_bf16(afr[at], bfr, acc2[at][ct]);
        }
    }
    #pragma unroll
    for (int ct = 0; ct < 8; ++ct) {
        const int col = w * 128 + ct * 16 + c;
        const float bv = bo[col];
        #pragma unroll
        for (int at = 0; at < 2; ++at)
            #pragma unroll
            for (int r = 0; r < 4; ++r) {
                const int n = nt * 32 + at * 16 + g * 4 + r;
                outp[(size_t)(b * 1024 + n) * 1024 + col] = acc2[at][ct][r] + bv;
            }
    }
}

extern "C" void kernel_launch(void* const* d_in, const int* in_sizes, int n_in,
                              void* d_out, int out_size, void* d_ws, size_t ws_size,
                              hipStream_t stream)
{
    (void)in_sizes; (void)n_in; (void)out_size; (void)ws_size;
    const float* query = (const float*)d_in[0];
    const float* key   = (const float*)d_in[1];
    const float* value = (const float*)d_in[2];
    const float* w_q = (const float*)d_in[3];
    const float* b_q = (const float*)d_in[4];
    const float* w_k = (const float*)d_in[5];
    const float* b_k = (const float*)d_in[6];
    const float* w_v = (const float*)d_in[7];
    const float* b_v = (const float*)d_in[8];
    const float* w_o = (const float*)d_in[9];
    const float* b_o = (const float*)d_in[10];

    float* out = (float*)d_out;              // out0 [0,8M) floats; out1 [8M,16M)
    short* vf  = (short*)d_out;              // V frags hosted in out0 (16.78MB)
    short* qf  = (short*)(out + 8388608);    // Q frags hosted in out1 lower half
    short* kf  = qf + 8388608;               // K frags hosted in out1 upper half
    short* wof = (short*)d_ws;               // w_o bf16 frags (2MB — only ws use)

    wo_conv_kernel<<<dim3(512), 256, 0, stream>>>(w_o, wof);

    dim3 pgrid(8, 64);  // x = col tile (1024/128), y = row tile (8192/128)
    proj_kernel<0><<<pgrid, 256, 0, stream>>>(query, w_q, b_q, qf);
    proj_kernel<1><<<pgrid, 256, 0, stream>>>(key,   w_k, b_k, kf);
    proj_kernel<2><<<pgrid, 256, 0, stream>>>(value, w_v, b_v, vf);

    void* args[] = { (void*)&qf, (void*)&kf, (void*)&vf,
                     (void*)&wof, (void*)&b_o, (void*)&out };
    hipLaunchCooperativeKernel(attn_kernel, dim3(256), dim3(512), args, 0u, stream);
}